// Round 8
// baseline (12607.986 us; speedup 1.0000x reference)
//
#include <hip/hip_runtime.h>
#include <hip/hip_fp16.h>
#include <cstdint>
#include <cstddef>

#define NN 50000
#define EE 800000
#define NNZ (NN + EE)
#define KK 20
#define TPK 30
#define P1B 64
#define P1CH ((NN + P1B - 1) / P1B)  // 782
#define SCB 256
#define SCNB ((NN + SCB - 1) / SCB)  // 196
#define PGRID 1024
#define PWAVES (PGRID * 4)                 // 4096 persistent waves
#define NPW ((NN + PWAVES - 1) / PWAVES)   // 13 nodes per wave

// ---------------- fp16 helpers ----------------

__device__ __forceinline__ float2 h2f(unsigned int u) {
  __half2 h = *reinterpret_cast<__half2*>(&u);
  return __half22float2(h);
}
__device__ __forceinline__ unsigned int f2h(float a, float b) {
  __half2 h = __floats2half2_rn(a, b);
  return *reinterpret_cast<unsigned int*>(&h);
}

// ---------------- device-scope grid barrier ----------------
// Sense-reversing barrier. Requires all PGRID blocks co-resident
// (guaranteed: 256 thr, launch_bounds(256,4) => <=128 VGPR => 4 blocks/CU,
// LDS 0, grid = 4*256). AGENT-scope release/acquire provides cross-XCD
// L2 writeback/invalidate so sweep k+1 reads sweep k's data coherently.
__device__ __forceinline__ void gridbar(int* cnt, int* gen, int nb) {
  __syncthreads();
  if (threadIdx.x == 0) {
    int g = __hip_atomic_load(gen, __ATOMIC_RELAXED, __HIP_MEMORY_SCOPE_AGENT);
    int a = __hip_atomic_fetch_add(cnt, 1, __ATOMIC_ACQ_REL, __HIP_MEMORY_SCOPE_AGENT);
    if (a == nb - 1) {
      __hip_atomic_store(cnt, 0, __ATOMIC_RELAXED, __HIP_MEMORY_SCOPE_AGENT);
      __hip_atomic_store(gen, g + 1, __ATOMIC_RELEASE, __HIP_MEMORY_SCOPE_AGENT);
    } else {
      while (__hip_atomic_load(gen, __ATOMIC_RELAXED, __HIP_MEMORY_SCOPE_AGENT) == g)
        __builtin_amdgcn_s_sleep(2);
      (void)__hip_atomic_load(gen, __ATOMIC_ACQUIRE, __HIP_MEMORY_SCOPE_AGENT);
    }
  }
  __syncthreads();
}

// ---------------- preprocessing ----------------

__global__ __launch_bounds__(256) void init_deg(int* deg) {
  int t = blockIdx.x * 256 + threadIdx.x;
  if (t < NN) deg[t] = 1;  // self-loop
}

__global__ __launch_bounds__(256) void count_deg(const int* __restrict__ ecol, int* deg) {
  int t = blockIdx.x * 256 + threadIdx.x;
  if (t < EE) atomicAdd(&deg[ecol[t]], 1);
}

__global__ __launch_bounds__(256) void scan_bsum(const int* __restrict__ deg, int* __restrict__ bsum) {
  __shared__ int red[256];
  int tid = threadIdx.x;
  int t = blockIdx.x * 256 + tid;
  red[tid] = (t < NN) ? deg[t] : 0;
  __syncthreads();
  for (int o = 128; o > 0; o >>= 1) {
    if (tid < o) red[tid] += red[tid + o];
    __syncthreads();
  }
  if (tid == 0) bsum[blockIdx.x] = red[0];
}

__global__ __launch_bounds__(256) void scan_boff(const int* __restrict__ bsum, int* __restrict__ boff) {
  __shared__ int s[256];
  int tid = threadIdx.x;
  int own = (tid < SCNB) ? bsum[tid] : 0;
  s[tid] = own;
  __syncthreads();
  for (int o = 1; o < 256; o <<= 1) {
    int v = s[tid];
    int u = (tid >= o) ? s[tid - o] : 0;
    __syncthreads();
    s[tid] = v + u;
    __syncthreads();
  }
  if (tid < SCNB) boff[tid] = s[tid] - own;  // exclusive
}

__global__ __launch_bounds__(256) void scan_write(const int* __restrict__ deg,
                                                  const int* __restrict__ boff,
                                                  int* __restrict__ rowptr, int* __restrict__ cursor,
                                                  float* __restrict__ dinv) {
  __shared__ int s[256];
  int tid = threadIdx.x;
  int t = blockIdx.x * 256 + tid;
  int d = (t < NN) ? deg[t] : 0;
  s[tid] = d;
  __syncthreads();
  for (int o = 1; o < 256; o <<= 1) {
    int v = s[tid];
    int u = (tid >= o) ? s[tid - o] : 0;
    __syncthreads();
    s[tid] = v + u;
    __syncthreads();
  }
  if (t < NN) {
    int excl = boff[blockIdx.x] + s[tid] - d;
    rowptr[t] = excl;
    cursor[t] = excl;
    dinv[t] = 1.0f / sqrtf((float)d);
    if (t == NN - 1) rowptr[NN] = excl + d;
  }
}

__global__ __launch_bounds__(256) void scatter_csr(const int* __restrict__ erow,
                                                   const int* __restrict__ ecol,
                                                   const float* __restrict__ dinv, int* cursor,
                                                   int2* __restrict__ meta) {
  int t = blockIdx.x * 256 + threadIdx.x;
  if (t < EE) {
    int r = erow[t], c = ecol[t];
    int p = atomicAdd(&cursor[c], 1);
    meta[p] = make_int2(r, __float_as_int(dinv[r] * dinv[c]));
  } else if (t < NNZ) {
    int i = t - EE;
    int p = atomicAdd(&cursor[i], 1);
    meta[p] = make_int2(i, __float_as_int(dinv[i] * dinv[i]));
  }
}

__global__ __launch_bounds__(256) void extract_x0(const float* __restrict__ x, float4* __restrict__ x0) {
  int t = blockIdx.x * 256 + threadIdx.x;
  if (t < NN) x0[t] = *(const float4*)&x[(size_t)t * 8];
}

// ---------------- persistent 64-ch fp16 layer kernel ----------------
// Runs all KK sweeps of one layer: t_k = S t_{k-1} + x (19x), then
// out_f32 = coef * (S t_19) + alpha * x_f32. One wave owns NPW nodes for the
// whole layer; degree + the <=64-edge meta chunk persist in registers.
// Lane = (e8 edge-slot, c8 channel-group). All shuffle trip counts are
// wave-uniform; lanes >= nj hold (src=0, w=0).
__global__ __launch_bounds__(256, 4) void sweep64h_layer(
    const uint4* __restrict__ xh,      // fp16 x (layer input)
    const float4* __restrict__ xf,     // f32 x (for final combine)
    uint4* __restrict__ tpA, uint4* __restrict__ tpB,  // fp16 ping-pong
    float4* __restrict__ toutf,        // f32 final output
    const int* __restrict__ rowptr, const int2* __restrict__ meta,
    float coef, float alpha, int* bar_cnt, int* bar_gen) {
  int lane = threadIdx.x & 63;
  int w = threadIdx.x >> 6;
  int wid = blockIdx.x * 4 + w;
  int c8 = lane & 7;
  int e8 = lane >> 3;
  int vbase = wid * NPW;

  int dg[NPW];
  int2 mL[NPW];
#pragma unroll
  for (int n = 0; n < NPW; ++n) {
    int v = vbase + n;
    int d = 0;
    int2 m = make_int2(0, 0);
    if (v < NN) {
      int s = rowptr[v], e = rowptr[v + 1];
      d = e - s;
      int nj = (d > 64) ? 64 : d;
      if (lane < nj) m = meta[s + lane];
    }
    dg[n] = d;
    mL[n] = m;
  }

  const uint4* cur = xh;
  uint4* nxt = tpA;
  for (int k = 1; k <= KK; ++k) {
    bool fin = (k == KK);
#pragma unroll
    for (int n = 0; n < NPW; ++n) {
      int v = vbase + n;
      if (v >= NN) continue;  // wave-uniform
      int d = dg[n];
      int nj = (d > 64) ? 64 : d;
      float a0 = 0.f, a1 = 0.f, a2 = 0.f, a3 = 0.f;
      float a4 = 0.f, a5 = 0.f, a6 = 0.f, a7 = 0.f;
      int T = (nj + 7) >> 3;
      int t = 0;
      for (; t + 1 < T; t += 2) {
        int j0 = e8 + 8 * t;
        int j1 = j0 + 8;
        int s0 = __shfl(mL[n].x, j0);
        int s1 = __shfl(mL[n].x, j1);
        float w0 = __int_as_float(__shfl(mL[n].y, j0));
        float w1 = __int_as_float(__shfl(mL[n].y, j1));
        uint4 q0 = cur[(size_t)s0 * 8 + c8];
        uint4 q1 = cur[(size_t)s1 * 8 + c8];
        float2 f;
        f = h2f(q0.x); a0 = fmaf(w0, f.x, a0); a1 = fmaf(w0, f.y, a1);
        f = h2f(q0.y); a2 = fmaf(w0, f.x, a2); a3 = fmaf(w0, f.y, a3);
        f = h2f(q0.z); a4 = fmaf(w0, f.x, a4); a5 = fmaf(w0, f.y, a5);
        f = h2f(q0.w); a6 = fmaf(w0, f.x, a6); a7 = fmaf(w0, f.y, a7);
        f = h2f(q1.x); a0 = fmaf(w1, f.x, a0); a1 = fmaf(w1, f.y, a1);
        f = h2f(q1.y); a2 = fmaf(w1, f.x, a2); a3 = fmaf(w1, f.y, a3);
        f = h2f(q1.z); a4 = fmaf(w1, f.x, a4); a5 = fmaf(w1, f.y, a5);
        f = h2f(q1.w); a6 = fmaf(w1, f.x, a6); a7 = fmaf(w1, f.y, a7);
      }
      if (t < T) {
        int j0 = e8 + 8 * t;
        int s0 = __shfl(mL[n].x, j0);
        float w0 = __int_as_float(__shfl(mL[n].y, j0));
        uint4 q0 = cur[(size_t)s0 * 8 + c8];
        float2 f;
        f = h2f(q0.x); a0 = fmaf(w0, f.x, a0); a1 = fmaf(w0, f.y, a1);
        f = h2f(q0.y); a2 = fmaf(w0, f.x, a2); a3 = fmaf(w0, f.y, a3);
        f = h2f(q0.z); a4 = fmaf(w0, f.x, a4); a5 = fmaf(w0, f.y, a5);
        f = h2f(q0.w); a6 = fmaf(w0, f.x, a6); a7 = fmaf(w0, f.y, a7);
      }
      if (d > 64) {  // overflow chunks (statistically never at mean deg ~17)
        int s = rowptr[v];
        int e = s + d;
        for (int b2 = s + 64; b2 < e; b2 += 64) {
          int nj2 = e - b2;
          if (nj2 > 64) nj2 = 64;
          int2 mX = (lane < nj2) ? meta[b2 + lane] : make_int2(0, 0);
          int T2 = (nj2 + 7) >> 3;
          for (int t2 = 0; t2 < T2; ++t2) {
            int j0 = e8 + 8 * t2;
            int s0 = __shfl(mX.x, j0);
            float w0 = __int_as_float(__shfl(mX.y, j0));
            uint4 q0 = cur[(size_t)s0 * 8 + c8];
            float2 f;
            f = h2f(q0.x); a0 = fmaf(w0, f.x, a0); a1 = fmaf(w0, f.y, a1);
            f = h2f(q0.y); a2 = fmaf(w0, f.x, a2); a3 = fmaf(w0, f.y, a3);
            f = h2f(q0.z); a4 = fmaf(w0, f.x, a4); a5 = fmaf(w0, f.y, a5);
            f = h2f(q0.w); a6 = fmaf(w0, f.x, a6); a7 = fmaf(w0, f.y, a7);
          }
        }
      }
      // reduce across the 8 e-slots (lane bits 3..5)
#pragma unroll
      for (int o = 8; o <= 32; o <<= 1) {
        a0 += __shfl_xor(a0, o); a1 += __shfl_xor(a1, o);
        a2 += __shfl_xor(a2, o); a3 += __shfl_xor(a3, o);
        a4 += __shfl_xor(a4, o); a5 += __shfl_xor(a5, o);
        a6 += __shfl_xor(a6, o); a7 += __shfl_xor(a7, o);
      }
      if (e8 == 0) {
        if (!fin) {
          uint4 xq = xh[(size_t)v * 8 + c8];
          float2 f;
          f = h2f(xq.x); float o0 = a0 + f.x, o1 = a1 + f.y;
          f = h2f(xq.y); float o2 = a2 + f.x, o3 = a3 + f.y;
          f = h2f(xq.z); float o4 = a4 + f.x, o5 = a5 + f.y;
          f = h2f(xq.w); float o6 = a6 + f.x, o7 = a7 + f.y;
          uint4 r;
          r.x = f2h(o0, o1); r.y = f2h(o2, o3);
          r.z = f2h(o4, o5); r.w = f2h(o6, o7);
          nxt[(size_t)v * 8 + c8] = r;
        } else {
          float4 x0v = xf[(size_t)v * 16 + c8 * 2];
          float4 x1v = xf[(size_t)v * 16 + c8 * 2 + 1];
          float4 r0, r1;
          r0.x = coef * a0 + alpha * x0v.x; r0.y = coef * a1 + alpha * x0v.y;
          r0.z = coef * a2 + alpha * x0v.z; r0.w = coef * a3 + alpha * x0v.w;
          r1.x = coef * a4 + alpha * x1v.x; r1.y = coef * a5 + alpha * x1v.y;
          r1.z = coef * a6 + alpha * x1v.z; r1.w = coef * a7 + alpha * x1v.w;
          toutf[(size_t)v * 16 + c8 * 2] = r0;
          toutf[(size_t)v * 16 + c8 * 2 + 1] = r1;
        }
      }
    }
    if (!fin) {
      gridbar(bar_cnt, bar_gen, PGRID);
      cur = nxt;
      nxt = (cur == tpA) ? tpB : tpA;
    }
  }
}

// 4-channel f32: wave = 16 nodes x 4 edge slots; unrolled x4 (no in-loop shuffles).
__global__ __launch_bounds__(256) void sweep4(const float4* __restrict__ tin,
                                              const float4* __restrict__ xin,
                                              float4* __restrict__ tout,
                                              const int* __restrict__ rowptr,
                                              const int2* __restrict__ meta,
                                              float aacc, float axc) {
  int lane = threadIdx.x & 63;
  int w = threadIdx.x >> 6;
  int n16 = lane & 15;
  int e4 = lane >> 4;
  int v = (blockIdx.x * 4 + w) * 16 + n16;
  int vv = (v < NN) ? v : (NN - 1);
  int s = rowptr[vv], e = rowptr[vv + 1];
  float a0 = 0.f, a1 = 0.f, a2 = 0.f, a3 = 0.f;
  float b0 = 0.f, b1 = 0.f, b2 = 0.f, b3 = 0.f;
  int i = s + e4;
  for (; i + 12 < e; i += 16) {
    int2 m0 = meta[i];
    int2 m1 = meta[i + 4];
    int2 m2 = meta[i + 8];
    int2 m3 = meta[i + 12];
    float w0 = __int_as_float(m0.y);
    float w1 = __int_as_float(m1.y);
    float w2 = __int_as_float(m2.y);
    float w3 = __int_as_float(m3.y);
    float4 t0 = tin[m0.x];
    float4 t1 = tin[m1.x];
    float4 t2 = tin[m2.x];
    float4 t3 = tin[m3.x];
    a0 = fmaf(w0, t0.x, a0); a1 = fmaf(w0, t0.y, a1);
    a2 = fmaf(w0, t0.z, a2); a3 = fmaf(w0, t0.w, a3);
    b0 = fmaf(w1, t1.x, b0); b1 = fmaf(w1, t1.y, b1);
    b2 = fmaf(w1, t1.z, b2); b3 = fmaf(w1, t1.w, b3);
    a0 = fmaf(w2, t2.x, a0); a1 = fmaf(w2, t2.y, a1);
    a2 = fmaf(w2, t2.z, a2); a3 = fmaf(w2, t2.w, a3);
    b0 = fmaf(w3, t3.x, b0); b1 = fmaf(w3, t3.y, b1);
    b2 = fmaf(w3, t3.z, b2); b3 = fmaf(w3, t3.w, b3);
  }
  for (; i < e; i += 4) {
    int2 m0 = meta[i];
    float w0 = __int_as_float(m0.y);
    float4 t0 = tin[m0.x];
    a0 = fmaf(w0, t0.x, a0); a1 = fmaf(w0, t0.y, a1);
    a2 = fmaf(w0, t0.z, a2); a3 = fmaf(w0, t0.w, a3);
  }
  a0 += b0; a1 += b1; a2 += b2; a3 += b3;
  a0 += __shfl_xor(a0, 16); a1 += __shfl_xor(a1, 16);
  a2 += __shfl_xor(a2, 16); a3 += __shfl_xor(a3, 16);
  a0 += __shfl_xor(a0, 32); a1 += __shfl_xor(a1, 32);
  a2 += __shfl_xor(a2, 32); a3 += __shfl_xor(a3, 32);
  if (e4 == 0 && v < NN) {
    float4 xv = xin[v];
    float4 o;
    o.x = aacc * a0 + axc * xv.x;
    o.y = aacc * a1 + axc * xv.y;
    o.z = aacc * a2 + axc * xv.z;
    o.w = aacc * a3 + axc * xv.w;
    tout[v] = o;
  }
}

// ---------------- dense layers ----------------

// emits f32 out AND fp16 copy for the next layer's propagation
__global__ __launch_bounds__(256) void dense4(const float* __restrict__ h4,
                                              const float* __restrict__ W,  // [64][4]
                                              const float* __restrict__ b,
                                              float* __restrict__ out,
                                              unsigned int* __restrict__ outh) {
  __shared__ float sWt[4 * 64];
  int tid = threadIdx.x;
  {
    int j = tid >> 2, c = tid & 3;
    sWt[c * 64 + j] = W[tid];
  }
  __syncthreads();
  int lane = tid & 63, w = tid >> 6;
  int n = blockIdx.x * 4 + w;
  if (n >= NN) return;  // wave-uniform
  float acc = b[lane];
#pragma unroll
  for (int c = 0; c < 4; ++c)
    acc = fmaf(h4[(size_t)n * 4 + c], sWt[c * 64 + lane], acc);
  acc = fmaxf(acc, 0.f);
  out[(size_t)n * 64 + lane] = acc;
  int p = lane & 31;
  float va = __shfl(acc, 2 * p);
  float vb = __shfl(acc, 2 * p + 1);
  if (lane < 32) outh[(size_t)n * 32 + lane] = f2h(va, vb);
}

// 128 nodes per block; thread = (node j, out-quarter q) covering nodes {j, j+64}
#define DN 128
__global__ __launch_bounds__(256) void dense64(const float* __restrict__ h,
                                               const float* __restrict__ W,  // [64][64]
                                               const float* __restrict__ b,
                                               const float* __restrict__ resid,
                                               float* __restrict__ out,
                                               uint4* __restrict__ outh,  // optional fp16 copy
                                               int doRelu, int doResid) {
  __shared__ float sX[64 * 130];
  __shared__ float sWt[64 * 68];
  int tid = threadIdx.x;
  int base = blockIdx.x * DN;
  for (int i = tid; i < 64 * 64; i += 256) {
    int o = i >> 6, c = i & 63;
    sWt[c * 68 + o] = W[i];
  }
  for (int i = tid; i < DN * 64; i += 256) {
    int node = i >> 6, c = i & 63;
    int n = base + node;
    sX[c * 130 + node] = (n < NN) ? h[(size_t)n * 64 + c] : 0.f;
  }
  __syncthreads();
  int j = tid & 63;
  int q = tid >> 6;
  float acc0[16], acc1[16];
#pragma unroll
  for (int o = 0; o < 16; ++o) { acc0[o] = b[q * 16 + o]; acc1[o] = acc0[o]; }
  for (int c = 0; c < 64; ++c) {
    float x0 = sX[c * 130 + j];
    float x1 = sX[c * 130 + 64 + j];
#pragma unroll
    for (int o4 = 0; o4 < 4; ++o4) {
      float4 wv = *(const float4*)&sWt[c * 68 + q * 16 + o4 * 4];
      acc0[o4 * 4 + 0] = fmaf(x0, wv.x, acc0[o4 * 4 + 0]);
      acc0[o4 * 4 + 1] = fmaf(x0, wv.y, acc0[o4 * 4 + 1]);
      acc0[o4 * 4 + 2] = fmaf(x0, wv.z, acc0[o4 * 4 + 2]);
      acc0[o4 * 4 + 3] = fmaf(x0, wv.w, acc0[o4 * 4 + 3]);
      acc1[o4 * 4 + 0] = fmaf(x1, wv.x, acc1[o4 * 4 + 0]);
      acc1[o4 * 4 + 1] = fmaf(x1, wv.y, acc1[o4 * 4 + 1]);
      acc1[o4 * 4 + 2] = fmaf(x1, wv.z, acc1[o4 * 4 + 2]);
      acc1[o4 * 4 + 3] = fmaf(x1, wv.w, acc1[o4 * 4 + 3]);
    }
  }
  int n0 = base + j, n1 = base + 64 + j;
#pragma unroll
  for (int half = 0; half < 2; ++half) {
    int n = half ? n1 : n0;
    float* acc = half ? acc1 : acc0;
    if (n < NN) {
      if (doRelu) {
#pragma unroll
        for (int o = 0; o < 16; ++o) acc[o] = fmaxf(acc[o], 0.f);
      }
      if (doResid) {
#pragma unroll
        for (int o4 = 0; o4 < 4; ++o4) {
          float4 rv = *(const float4*)&resid[(size_t)n * 64 + q * 16 + o4 * 4];
          acc[o4 * 4 + 0] += rv.x; acc[o4 * 4 + 1] += rv.y;
          acc[o4 * 4 + 2] += rv.z; acc[o4 * 4 + 3] += rv.w;
        }
      }
#pragma unroll
      for (int o4 = 0; o4 < 4; ++o4) {
        float4 r;
        r.x = acc[o4 * 4 + 0]; r.y = acc[o4 * 4 + 1];
        r.z = acc[o4 * 4 + 2]; r.w = acc[o4 * 4 + 3];
        *(float4*)&out[(size_t)n * 64 + q * 16 + o4 * 4] = r;
      }
      if (outh) {
        uint4 u;
        u.x = f2h(acc[0], acc[1]);  u.y = f2h(acc[2], acc[3]);
        u.z = f2h(acc[4], acc[5]);  u.w = f2h(acc[6], acc[7]);
        outh[(size_t)n * 8 + q * 2] = u;
        u.x = f2h(acc[8], acc[9]);  u.y = f2h(acc[10], acc[11]);
        u.z = f2h(acc[12], acc[13]); u.w = f2h(acc[14], acc[15]);
        outh[(size_t)n * 8 + q * 2 + 1] = u;
      }
    }
  }
}

// ---------------- scoring / selection / output ----------------

__global__ __launch_bounds__(256) void score_k(const float* __restrict__ y,
                                               const float* __restrict__ wp,
                                               float* __restrict__ scores) {
  int tid = threadIdx.x;
  int lane = tid & 63, w = tid >> 6;
  int n = blockIdx.x * 4 + w;
  if (n >= NN) return;
  float wv = wp[lane];
  float s = wv * wv;
#pragma unroll
  for (int o = 32; o > 0; o >>= 1) s += __shfl_xor(s, o);
  float invn = 1.0f / sqrtf(s);
  float p = y[(size_t)n * 64 + lane] * wv;
#pragma unroll
  for (int o = 32; o > 0; o >>= 1) p += __shfl_xor(p, o);
  if (lane == 0) scores[n] = tanhf(p * invn);
}

__device__ __forceinline__ bool lexgt(float v1, int i1, float v2, int i2) {
  return (v1 > v2) || (v1 == v2 && i1 < i2);
}

// phase 1: 64 single-wave blocks, each emits its chunk's top-30.
__global__ __launch_bounds__(64, 1) void topk_p1(const float* __restrict__ score,
                                                 float* __restrict__ candv,
                                                 int* __restrict__ candi) {
  int lane = threadIdx.x;
  int base = blockIdx.x * P1CH;
  float lv[TPK]; int li[TPK];
#pragma unroll
  for (int k = 0; k < TPK; ++k) { lv[k] = -3.4e38f; li[k] = 0x7FFFFFFF; }
  for (int k = lane; k < P1CH; k += 64) {
    int idx = base + k;
    if (idx >= NN) break;
    float v = score[idx];
    if (lexgt(v, idx, lv[TPK - 1], li[TPK - 1])) {
      float cv = v; int ci = idx;
#pragma unroll
      for (int m = 0; m < TPK; ++m) {
        bool sw = lexgt(cv, ci, lv[m], li[m]);
        float tv = sw ? lv[m] : cv; int ti = sw ? li[m] : ci;
        lv[m] = sw ? cv : lv[m]; li[m] = sw ? ci : li[m];
        cv = tv; ci = ti;
      }
    }
  }
  for (int r = 0; r < TPK; ++r) {
    float bv = lv[0]; int bi = li[0];
#pragma unroll
    for (int o = 32; o > 0; o >>= 1) {
      float ov = __shfl_xor(bv, o); int oi = __shfl_xor(bi, o);
      if (lexgt(ov, oi, bv, bi)) { bv = ov; bi = oi; }
    }
    if (lane == 0) { candv[blockIdx.x * TPK + r] = bv; candi[blockIdx.x * TPK + r] = bi; }
    bool mine = (li[0] == bi);
#pragma unroll
    for (int m = 0; m < TPK - 1; ++m) {
      lv[m] = mine ? lv[m + 1] : lv[m];
      li[m] = mine ? li[m + 1] : li[m];
    }
    if (mine) { lv[TPK - 1] = -3.4e38f; li[TPK - 1] = 0x7FFFFFFF; }
  }
}

// phase 2 + final output
__global__ __launch_bounds__(64, 1) void topk_p2_final(const float* __restrict__ candv,
                                                       const int* __restrict__ candi,
                                                       const float* __restrict__ y,
                                                       float* __restrict__ out) {
  __shared__ float sV[TPK];
  __shared__ int sI[TPK];
  int lane = threadIdx.x;  // 64
  float lv[TPK]; int li[TPK];
#pragma unroll
  for (int k = 0; k < TPK; ++k) { lv[k] = -3.4e38f; li[k] = 0x7FFFFFFF; }
  for (int k = lane; k < P1B * TPK; k += 64) {
    float v = candv[k]; int id = candi[k];
    if (lexgt(v, id, lv[TPK - 1], li[TPK - 1])) {
      float cv = v; int ci = id;
#pragma unroll
      for (int m = 0; m < TPK; ++m) {
        bool sw = lexgt(cv, ci, lv[m], li[m]);
        float tv = sw ? lv[m] : cv; int ti = sw ? li[m] : ci;
        lv[m] = sw ? cv : lv[m]; li[m] = sw ? ci : li[m];
        cv = tv; ci = ti;
      }
    }
  }
  for (int r = 0; r < TPK; ++r) {
    float bv = lv[0]; int bi = li[0];
#pragma unroll
    for (int o = 32; o > 0; o >>= 1) {
      float ov = __shfl_xor(bv, o); int oi = __shfl_xor(bi, o);
      if (lexgt(ov, oi, bv, bi)) { bv = ov; bi = oi; }
    }
    if (lane == 0) { sV[r] = bv; sI[r] = bi; }
    bool mine = (li[0] == bi);
#pragma unroll
    for (int m = 0; m < TPK - 1; ++m) {
      lv[m] = mine ? lv[m + 1] : lv[m];
      li[m] = mine ? li[m + 1] : li[m];
    }
    if (mine) { lv[TPK - 1] = -3.4e38f; li[TPK - 1] = 0x7FFFFFFF; }
  }
  __syncthreads();
  float m = -3.4e38f;
  for (int r = 0; r < TPK; ++r)
    m = fmaxf(m, y[(size_t)sI[r] * 64 + lane] * sV[r]);
  out[lane] = m;
}

// ---------------- host orchestration ----------------

extern "C" void kernel_launch(void* const* d_in, const int* in_sizes, int n_in,
                              void* d_out, int out_size, void* d_ws, size_t ws_size,
                              hipStream_t stream) {
  const float* x = (const float*)d_in[0];
  const int* ei = (const int*)d_in[1];
  const float* Wl[5] = {(const float*)d_in[2], (const float*)d_in[4], (const float*)d_in[6],
                        (const float*)d_in[8], (const float*)d_in[10]};
  const float* bl[5] = {(const float*)d_in[3], (const float*)d_in[5], (const float*)d_in[7],
                        (const float*)d_in[9], (const float*)d_in[11]};
  const float* Wm = (const float*)d_in[12];
  const float* bm = (const float*)d_in[13];
  const float* wp = (const float*)d_in[14];
  float* out = (float*)d_out;

  uint8_t* base = (uint8_t*)d_ws;
  size_t off = 0;
  auto alloc = [&](size_t bytes) -> void* {
    void* p = base + off;
    off += (bytes + 255) & ~(size_t)255;
    return p;
  };
  int* deg = (int*)alloc(NN * 4);
  int* rowptr = (int*)alloc((NN + 1) * 4);
  int* cursor = (int*)alloc(NN * 4);
  float* dinv = (float*)alloc(NN * 4);
  int* bsum = (int*)alloc(SCNB * 4);
  int* boff = (int*)alloc(SCNB * 4);
  int2* meta = (int2*)alloc((size_t)NNZ * 8);
  float* x0 = (float*)alloc((size_t)NN * 4 * 4);
  float* t4a = (float*)alloc((size_t)NN * 4 * 4);
  float* t4b = (float*)alloc((size_t)NN * 4 * 4);
  float* xcur = (float*)alloc((size_t)NN * 64 * 4);
  float* tA = (float*)alloc((size_t)NN * 64 * 4);
  uint4* xh = (uint4*)alloc((size_t)NN * 64 * 2);   // fp16 x copy
  uint4* thA = (uint4*)alloc((size_t)NN * 64 * 2);  // fp16 state ping
  uint4* thB = (uint4*)alloc((size_t)NN * 64 * 2);  // fp16 state pong
  float* scores = (float*)alloc(NN * 4);
  float* candv = (float*)alloc((size_t)P1B * TPK * 4);
  int* candi = (int*)alloc((size_t)P1B * TPK * 4);
  int* barv = (int*)alloc(256);  // [0]=cnt, [1]=gen

  const int* erow = ei;
  const int* ecol = ei + EE;

  hipMemsetAsync(barv, 0, 8, stream);  // cnt=0, gen=0 each call

  init_deg<<<(NN + 255) / 256, 256, 0, stream>>>(deg);
  count_deg<<<(EE + 255) / 256, 256, 0, stream>>>(ecol, deg);
  scan_bsum<<<SCNB, 256, 0, stream>>>(deg, bsum);
  scan_boff<<<1, 256, 0, stream>>>(bsum, boff);
  scan_write<<<SCNB, 256, 0, stream>>>(deg, boff, rowptr, cursor, dinv);
  scatter_csr<<<(NNZ + 255) / 256, 256, 0, stream>>>(erow, ecol, dinv, cursor, meta);
  extract_x0<<<(NN + 255) / 256, 256, 0, stream>>>(x, (float4*)x0);

  const float AL[5] = {0.7f, 0.7f, 0.35f, 0.7f / 3.0f, 0.175f};

  // layer 0 (cin = 4, f32 — footprint is L2-resident)
  {
    float coef = (1.0f - AL[0]) / (float)KK;
    const float* tin = x0;
    float* tout = t4a;
    for (int k = 1; k <= KK; ++k) {
      float aacc = (k == KK) ? coef : 1.0f;
      float axc = (k == KK) ? AL[0] : 1.0f;
      sweep4<<<(NN + 63) / 64, 256, 0, stream>>>((const float4*)tin, (const float4*)x0,
                                                 (float4*)tout, rowptr, meta, aacc, axc);
      tin = tout;
      tout = (tout == t4a) ? t4b : t4a;
    }
    dense4<<<(NN + 3) / 4, 256, 0, stream>>>(tin, Wl[0], bl[0], xcur, (unsigned int*)xh);
  }
  // layers 1..4: one persistent kernel per layer (all 20 sweeps + 19 grid barriers)
  for (int l = 1; l < 5; ++l) {
    float coef = (1.0f - AL[l]) / (float)KK;
    sweep64h_layer<<<PGRID, 256, 0, stream>>>(xh, (const float4*)xcur, thA, thB, (float4*)tA,
                                              rowptr, meta, coef, AL[l], &barv[0], &barv[1]);
    dense64<<<(NN + DN - 1) / DN, 256, 0, stream>>>(tA, Wl[l], bl[l], xcur, xcur,
                                                    (l < 4) ? xh : nullptr, 1, (l >= 2) ? 1 : 0);
  }
  // final projection y = x @ Wm.T + bm  -> tA
  dense64<<<(NN + DN - 1) / DN, 256, 0, stream>>>(xcur, Wm, bm, nullptr, tA, nullptr, 0, 0);
  score_k<<<(NN + 3) / 4, 256, 0, stream>>>(tA, wp, scores);
  topk_p1<<<P1B, 64, 0, stream>>>(scores, candv, candi);
  topk_p2_final<<<1, 64, 0, stream>>>(candv, candi, tA, out);
}

// Round 9
// 2080.944 us; speedup vs baseline: 6.0588x; 6.0588x over previous
//
#include <hip/hip_runtime.h>
#include <hip/hip_fp16.h>
#include <cstdint>
#include <cstddef>

#define NN 50000
#define EE 800000
#define NNZ (NN + EE)
#define KK 20
#define TPK 30
#define P1B 64
#define P1CH ((NN + P1B - 1) / P1B)  // 782
#define P1D 13                       // ceil(P1CH/64): max candidates a lane ingests
#define SCB 256
#define SCNB ((NN + SCB - 1) / SCB)  // 196

// ---------------- fp16 helpers ----------------

__device__ __forceinline__ float2 h2f(unsigned int u) {
  __half2 h = *reinterpret_cast<__half2*>(&u);
  return __half22float2(h);
}
__device__ __forceinline__ unsigned int f2h(float a, float b) {
  __half2 h = __floats2half2_rn(a, b);
  return *reinterpret_cast<unsigned int*>(&h);
}

// ---------------- preprocessing ----------------

__global__ __launch_bounds__(256) void init_deg(int* deg) {
  int t = blockIdx.x * 256 + threadIdx.x;
  if (t < NN) deg[t] = 1;  // self-loop
}

__global__ __launch_bounds__(256) void count_deg(const int* __restrict__ ecol, int* deg) {
  int t = blockIdx.x * 256 + threadIdx.x;
  if (t < EE) atomicAdd(&deg[ecol[t]], 1);
}

__global__ __launch_bounds__(256) void scan_bsum(const int* __restrict__ deg, int* __restrict__ bsum) {
  __shared__ int red[256];
  int tid = threadIdx.x;
  int t = blockIdx.x * 256 + tid;
  red[tid] = (t < NN) ? deg[t] : 0;
  __syncthreads();
  for (int o = 128; o > 0; o >>= 1) {
    if (tid < o) red[tid] += red[tid + o];
    __syncthreads();
  }
  if (tid == 0) bsum[blockIdx.x] = red[0];
}

__global__ __launch_bounds__(256) void scan_boff(const int* __restrict__ bsum, int* __restrict__ boff) {
  __shared__ int s[256];
  int tid = threadIdx.x;
  int own = (tid < SCNB) ? bsum[tid] : 0;
  s[tid] = own;
  __syncthreads();
  for (int o = 1; o < 256; o <<= 1) {
    int v = s[tid];
    int u = (tid >= o) ? s[tid - o] : 0;
    __syncthreads();
    s[tid] = v + u;
    __syncthreads();
  }
  if (tid < SCNB) boff[tid] = s[tid] - own;  // exclusive
}

__global__ __launch_bounds__(256) void scan_write(const int* __restrict__ deg,
                                                  const int* __restrict__ boff,
                                                  int* __restrict__ rowptr, int* __restrict__ cursor,
                                                  float* __restrict__ dinv) {
  __shared__ int s[256];
  int tid = threadIdx.x;
  int t = blockIdx.x * 256 + tid;
  int d = (t < NN) ? deg[t] : 0;
  s[tid] = d;
  __syncthreads();
  for (int o = 1; o < 256; o <<= 1) {
    int v = s[tid];
    int u = (tid >= o) ? s[tid - o] : 0;
    __syncthreads();
    s[tid] = v + u;
    __syncthreads();
  }
  if (t < NN) {
    int excl = boff[blockIdx.x] + s[tid] - d;
    rowptr[t] = excl;
    cursor[t] = excl;
    dinv[t] = 1.0f / sqrtf((float)d);
    if (t == NN - 1) rowptr[NN] = excl + d;
  }
}

__global__ __launch_bounds__(256) void scatter_csr(const int* __restrict__ erow,
                                                   const int* __restrict__ ecol,
                                                   const float* __restrict__ dinv, int* cursor,
                                                   int2* __restrict__ meta) {
  int t = blockIdx.x * 256 + threadIdx.x;
  if (t < EE) {
    int r = erow[t], c = ecol[t];
    int p = atomicAdd(&cursor[c], 1);
    meta[p] = make_int2(r, __float_as_int(dinv[r] * dinv[c]));
  } else if (t < NNZ) {
    int i = t - EE;
    int p = atomicAdd(&cursor[i], 1);
    meta[p] = make_int2(i, __float_as_int(dinv[i] * dinv[i]));
  }
}

__global__ __launch_bounds__(256) void extract_x0(const float* __restrict__ x, float4* __restrict__ x0) {
  int t = blockIdx.x * 256 + threadIdx.x;
  if (t < NN) x0[t] = *(const float4*)&x[(size_t)t * 8];
}

// ---------------- propagation sweeps ----------------
// tout[v] = aacc * sum_e nrm[e]*tin[src[e]] + axc * xin[v]

// 64-channel fp16 sweep, TWO nodes per wave (v0, v0+1): both meta loads issue
// together, both gather streams interleave -> 2x in-flight memory per wave.
// Lane = (e8 edge-slot, c8 channel-group). All shuffle trip counts are
// wave-uniform (rowptr values identical across lanes); lanes >= nj hold
// (src=0, w=0) so every __shfl runs with all 64 lanes active.
__global__ __launch_bounds__(256) void sweep64h(const uint4* __restrict__ tinq,
                                                const uint4* __restrict__ xinq,
                                                const float4* __restrict__ xinf,
                                                uint4* __restrict__ touth,
                                                float4* __restrict__ toutf,
                                                const int* __restrict__ rowptr,
                                                const int2* __restrict__ meta,
                                                float aacc, float axc, int isFinal) {
  int lane = threadIdx.x & 63;
  int w = threadIdx.x >> 6;
  int v0 = (blockIdx.x * 4 + w) * 2;  // grid exact: (NN/8) blocks, NN even
  int v1 = v0 + 1;
  if (v0 >= NN) return;
  int c8 = lane & 7;
  int e8 = lane >> 3;
  int s0 = rowptr[v0];
  int s1 = rowptr[v0 + 1];
  int e1 = rowptr[v0 + 2];
  int d0 = s1 - s0, d1 = e1 - s1;
  int nj0 = (d0 > 64) ? 64 : d0;
  int nj1 = (d1 > 64) ? 64 : d1;
  int2 mA = (lane < nj0) ? meta[s0 + lane] : make_int2(0, 0);
  int2 mB = (lane < nj1) ? meta[s1 + lane] : make_int2(0, 0);
  float a0 = 0.f, a1 = 0.f, a2 = 0.f, a3 = 0.f;
  float a4 = 0.f, a5 = 0.f, a6 = 0.f, a7 = 0.f;
  float b0 = 0.f, b1 = 0.f, b2 = 0.f, b3 = 0.f;
  float b4 = 0.f, b5 = 0.f, b6 = 0.f, b7 = 0.f;
  int T0 = (nj0 + 7) >> 3;
  int T1 = (nj1 + 7) >> 3;
  int Tc = (T0 < T1) ? T0 : T1;
  int t = 0;
  for (; t < Tc; ++t) {  // interleaved: 2 independent gathers in flight
    int j = e8 + 8 * t;
    int sa = __shfl(mA.x, j);
    int sb = __shfl(mB.x, j);
    float wa = __int_as_float(__shfl(mA.y, j));
    float wb = __int_as_float(__shfl(mB.y, j));
    uint4 qa = tinq[(size_t)sa * 8 + c8];
    uint4 qb = tinq[(size_t)sb * 8 + c8];
    float2 f;
    f = h2f(qa.x); a0 = fmaf(wa, f.x, a0); a1 = fmaf(wa, f.y, a1);
    f = h2f(qa.y); a2 = fmaf(wa, f.x, a2); a3 = fmaf(wa, f.y, a3);
    f = h2f(qa.z); a4 = fmaf(wa, f.x, a4); a5 = fmaf(wa, f.y, a5);
    f = h2f(qa.w); a6 = fmaf(wa, f.x, a6); a7 = fmaf(wa, f.y, a7);
    f = h2f(qb.x); b0 = fmaf(wb, f.x, b0); b1 = fmaf(wb, f.y, b1);
    f = h2f(qb.y); b2 = fmaf(wb, f.x, b2); b3 = fmaf(wb, f.y, b3);
    f = h2f(qb.z); b4 = fmaf(wb, f.x, b4); b5 = fmaf(wb, f.y, b5);
    f = h2f(qb.w); b6 = fmaf(wb, f.x, b6); b7 = fmaf(wb, f.y, b7);
  }
  for (; t < T0; ++t) {  // drain A (runs only if T0 > T1)
    int j = e8 + 8 * t;
    int sa = __shfl(mA.x, j);
    float wa = __int_as_float(__shfl(mA.y, j));
    uint4 qa = tinq[(size_t)sa * 8 + c8];
    float2 f;
    f = h2f(qa.x); a0 = fmaf(wa, f.x, a0); a1 = fmaf(wa, f.y, a1);
    f = h2f(qa.y); a2 = fmaf(wa, f.x, a2); a3 = fmaf(wa, f.y, a3);
    f = h2f(qa.z); a4 = fmaf(wa, f.x, a4); a5 = fmaf(wa, f.y, a5);
    f = h2f(qa.w); a6 = fmaf(wa, f.x, a6); a7 = fmaf(wa, f.y, a7);
  }
  for (; t < T1; ++t) {  // drain B (runs only if T1 > T0)
    int j = e8 + 8 * t;
    int sb = __shfl(mB.x, j);
    float wb = __int_as_float(__shfl(mB.y, j));
    uint4 qb = tinq[(size_t)sb * 8 + c8];
    float2 f;
    f = h2f(qb.x); b0 = fmaf(wb, f.x, b0); b1 = fmaf(wb, f.y, b1);
    f = h2f(qb.y); b2 = fmaf(wb, f.x, b2); b3 = fmaf(wb, f.y, b3);
    f = h2f(qb.z); b4 = fmaf(wb, f.x, b4); b5 = fmaf(wb, f.y, b5);
    f = h2f(qb.w); b6 = fmaf(wb, f.x, b6); b7 = fmaf(wb, f.y, b7);
  }
  // cold overflow path (deg > 64; statistically never at mean deg ~17)
  if (d0 > 64) {
    int e = s0 + d0;
    for (int c2 = s0 + 64; c2 < e; c2 += 64) {
      int nj2 = e - c2; if (nj2 > 64) nj2 = 64;
      int2 mX = (lane < nj2) ? meta[c2 + lane] : make_int2(0, 0);
      int T2 = (nj2 + 7) >> 3;
      for (int t2 = 0; t2 < T2; ++t2) {
        int j = e8 + 8 * t2;
        int sa = __shfl(mX.x, j);
        float wa = __int_as_float(__shfl(mX.y, j));
        uint4 qa = tinq[(size_t)sa * 8 + c8];
        float2 f;
        f = h2f(qa.x); a0 = fmaf(wa, f.x, a0); a1 = fmaf(wa, f.y, a1);
        f = h2f(qa.y); a2 = fmaf(wa, f.x, a2); a3 = fmaf(wa, f.y, a3);
        f = h2f(qa.z); a4 = fmaf(wa, f.x, a4); a5 = fmaf(wa, f.y, a5);
        f = h2f(qa.w); a6 = fmaf(wa, f.x, a6); a7 = fmaf(wa, f.y, a7);
      }
    }
  }
  if (d1 > 64) {
    int e = s1 + d1;
    for (int c2 = s1 + 64; c2 < e; c2 += 64) {
      int nj2 = e - c2; if (nj2 > 64) nj2 = 64;
      int2 mX = (lane < nj2) ? meta[c2 + lane] : make_int2(0, 0);
      int T2 = (nj2 + 7) >> 3;
      for (int t2 = 0; t2 < T2; ++t2) {
        int j = e8 + 8 * t2;
        int sb = __shfl(mX.x, j);
        float wb = __int_as_float(__shfl(mX.y, j));
        uint4 qb = tinq[(size_t)sb * 8 + c8];
        float2 f;
        f = h2f(qb.x); b0 = fmaf(wb, f.x, b0); b1 = fmaf(wb, f.y, b1);
        f = h2f(qb.y); b2 = fmaf(wb, f.x, b2); b3 = fmaf(wb, f.y, b3);
        f = h2f(qb.z); b4 = fmaf(wb, f.x, b4); b5 = fmaf(wb, f.y, b5);
        f = h2f(qb.w); b6 = fmaf(wb, f.x, b6); b7 = fmaf(wb, f.y, b7);
      }
    }
  }
  // reduce across the 8 e-slots (lane bits 3..5), both nodes interleaved
#pragma unroll
  for (int o = 8; o <= 32; o <<= 1) {
    a0 += __shfl_xor(a0, o); b0 += __shfl_xor(b0, o);
    a1 += __shfl_xor(a1, o); b1 += __shfl_xor(b1, o);
    a2 += __shfl_xor(a2, o); b2 += __shfl_xor(b2, o);
    a3 += __shfl_xor(a3, o); b3 += __shfl_xor(b3, o);
    a4 += __shfl_xor(a4, o); b4 += __shfl_xor(b4, o);
    a5 += __shfl_xor(a5, o); b5 += __shfl_xor(b5, o);
    a6 += __shfl_xor(a6, o); b6 += __shfl_xor(b6, o);
    a7 += __shfl_xor(a7, o); b7 += __shfl_xor(b7, o);
  }
  if (e8 == 0) {
    if (!isFinal) {
      uint4 xq0 = xinq[(size_t)v0 * 8 + c8];
      uint4 xq1 = xinq[(size_t)v1 * 8 + c8];
      float2 f;
      uint4 r;
      f = h2f(xq0.x); r.x = f2h(a0 + f.x, a1 + f.y);
      f = h2f(xq0.y); r.y = f2h(a2 + f.x, a3 + f.y);
      f = h2f(xq0.z); r.z = f2h(a4 + f.x, a5 + f.y);
      f = h2f(xq0.w); r.w = f2h(a6 + f.x, a7 + f.y);
      touth[(size_t)v0 * 8 + c8] = r;
      f = h2f(xq1.x); r.x = f2h(b0 + f.x, b1 + f.y);
      f = h2f(xq1.y); r.y = f2h(b2 + f.x, b3 + f.y);
      f = h2f(xq1.z); r.z = f2h(b4 + f.x, b5 + f.y);
      f = h2f(xq1.w); r.w = f2h(b6 + f.x, b7 + f.y);
      touth[(size_t)v1 * 8 + c8] = r;
    } else {
      float4 x0v = xinf[(size_t)v0 * 16 + c8 * 2];
      float4 x1v = xinf[(size_t)v0 * 16 + c8 * 2 + 1];
      float4 r0, r1;
      r0.x = aacc * a0 + axc * x0v.x; r0.y = aacc * a1 + axc * x0v.y;
      r0.z = aacc * a2 + axc * x0v.z; r0.w = aacc * a3 + axc * x0v.w;
      r1.x = aacc * a4 + axc * x1v.x; r1.y = aacc * a5 + axc * x1v.y;
      r1.z = aacc * a6 + axc * x1v.z; r1.w = aacc * a7 + axc * x1v.w;
      toutf[(size_t)v0 * 16 + c8 * 2] = r0;
      toutf[(size_t)v0 * 16 + c8 * 2 + 1] = r1;
      float4 y0v = xinf[(size_t)v1 * 16 + c8 * 2];
      float4 y1v = xinf[(size_t)v1 * 16 + c8 * 2 + 1];
      r0.x = aacc * b0 + axc * y0v.x; r0.y = aacc * b1 + axc * y0v.y;
      r0.z = aacc * b2 + axc * y0v.z; r0.w = aacc * b3 + axc * y0v.w;
      r1.x = aacc * b4 + axc * y1v.x; r1.y = aacc * b5 + axc * y1v.y;
      r1.z = aacc * b6 + axc * y1v.z; r1.w = aacc * b7 + axc * y1v.w;
      toutf[(size_t)v1 * 16 + c8 * 2] = r0;
      toutf[(size_t)v1 * 16 + c8 * 2 + 1] = r1;
    }
  }
}

// 4-channel f32: wave = 16 nodes x 4 edge slots; unrolled x4 (no in-loop shuffles).
__global__ __launch_bounds__(256) void sweep4(const float4* __restrict__ tin,
                                              const float4* __restrict__ xin,
                                              float4* __restrict__ tout,
                                              const int* __restrict__ rowptr,
                                              const int2* __restrict__ meta,
                                              float aacc, float axc) {
  int lane = threadIdx.x & 63;
  int w = threadIdx.x >> 6;
  int n16 = lane & 15;
  int e4 = lane >> 4;
  int v = (blockIdx.x * 4 + w) * 16 + n16;
  int vv = (v < NN) ? v : (NN - 1);
  int s = rowptr[vv], e = rowptr[vv + 1];
  float a0 = 0.f, a1 = 0.f, a2 = 0.f, a3 = 0.f;
  float b0 = 0.f, b1 = 0.f, b2 = 0.f, b3 = 0.f;
  int i = s + e4;
  for (; i + 12 < e; i += 16) {
    int2 m0 = meta[i];
    int2 m1 = meta[i + 4];
    int2 m2 = meta[i + 8];
    int2 m3 = meta[i + 12];
    float w0 = __int_as_float(m0.y);
    float w1 = __int_as_float(m1.y);
    float w2 = __int_as_float(m2.y);
    float w3 = __int_as_float(m3.y);
    float4 t0 = tin[m0.x];
    float4 t1 = tin[m1.x];
    float4 t2 = tin[m2.x];
    float4 t3 = tin[m3.x];
    a0 = fmaf(w0, t0.x, a0); a1 = fmaf(w0, t0.y, a1);
    a2 = fmaf(w0, t0.z, a2); a3 = fmaf(w0, t0.w, a3);
    b0 = fmaf(w1, t1.x, b0); b1 = fmaf(w1, t1.y, b1);
    b2 = fmaf(w1, t1.z, b2); b3 = fmaf(w1, t1.w, b3);
    a0 = fmaf(w2, t2.x, a0); a1 = fmaf(w2, t2.y, a1);
    a2 = fmaf(w2, t2.z, a2); a3 = fmaf(w2, t2.w, a3);
    b0 = fmaf(w3, t3.x, b0); b1 = fmaf(w3, t3.y, b1);
    b2 = fmaf(w3, t3.z, b2); b3 = fmaf(w3, t3.w, b3);
  }
  for (; i < e; i += 4) {
    int2 m0 = meta[i];
    float w0 = __int_as_float(m0.y);
    float4 t0 = tin[m0.x];
    a0 = fmaf(w0, t0.x, a0); a1 = fmaf(w0, t0.y, a1);
    a2 = fmaf(w0, t0.z, a2); a3 = fmaf(w0, t0.w, a3);
  }
  a0 += b0; a1 += b1; a2 += b2; a3 += b3;
  a0 += __shfl_xor(a0, 16); a1 += __shfl_xor(a1, 16);
  a2 += __shfl_xor(a2, 16); a3 += __shfl_xor(a3, 16);
  a0 += __shfl_xor(a0, 32); a1 += __shfl_xor(a1, 32);
  a2 += __shfl_xor(a2, 32); a3 += __shfl_xor(a3, 32);
  if (e4 == 0 && v < NN) {
    float4 xv = xin[v];
    float4 o;
    o.x = aacc * a0 + axc * xv.x;
    o.y = aacc * a1 + axc * xv.y;
    o.z = aacc * a2 + axc * xv.z;
    o.w = aacc * a3 + axc * xv.w;
    tout[v] = o;
  }
}

// ---------------- dense layers ----------------

// emits f32 out AND fp16 copy for the next layer's propagation
__global__ __launch_bounds__(256) void dense4(const float* __restrict__ h4,
                                              const float* __restrict__ W,  // [64][4]
                                              const float* __restrict__ b,
                                              float* __restrict__ out,
                                              unsigned int* __restrict__ outh) {
  __shared__ float sWt[4 * 64];
  int tid = threadIdx.x;
  {
    int j = tid >> 2, c = tid & 3;
    sWt[c * 64 + j] = W[tid];
  }
  __syncthreads();
  int lane = tid & 63, w = tid >> 6;
  int n = blockIdx.x * 4 + w;
  if (n >= NN) return;  // wave-uniform
  float acc = b[lane];
#pragma unroll
  for (int c = 0; c < 4; ++c)
    acc = fmaf(h4[(size_t)n * 4 + c], sWt[c * 64 + lane], acc);
  acc = fmaxf(acc, 0.f);
  out[(size_t)n * 64 + lane] = acc;
  int p = lane & 31;
  float va = __shfl(acc, 2 * p);
  float vb = __shfl(acc, 2 * p + 1);
  if (lane < 32) outh[(size_t)n * 32 + lane] = f2h(va, vb);
}

// 128 nodes per block; thread = (node j, out-quarter q) covering nodes {j, j+64}
#define DN 128
__global__ __launch_bounds__(256) void dense64(const float* __restrict__ h,
                                               const float* __restrict__ W,  // [64][64]
                                               const float* __restrict__ b,
                                               const float* __restrict__ resid,
                                               float* __restrict__ out,
                                               uint4* __restrict__ outh,  // optional fp16 copy
                                               int doRelu, int doResid) {
  __shared__ float sX[64 * 130];
  __shared__ float sWt[64 * 68];
  int tid = threadIdx.x;
  int base = blockIdx.x * DN;
  for (int i = tid; i < 64 * 64; i += 256) {
    int o = i >> 6, c = i & 63;
    sWt[c * 68 + o] = W[i];
  }
  for (int i = tid; i < DN * 64; i += 256) {
    int node = i >> 6, c = i & 63;
    int n = base + node;
    sX[c * 130 + node] = (n < NN) ? h[(size_t)n * 64 + c] : 0.f;
  }
  __syncthreads();
  int j = tid & 63;
  int q = tid >> 6;
  float acc0[16], acc1[16];
#pragma unroll
  for (int o = 0; o < 16; ++o) { acc0[o] = b[q * 16 + o]; acc1[o] = acc0[o]; }
  for (int c = 0; c < 64; ++c) {
    float x0 = sX[c * 130 + j];
    float x1 = sX[c * 130 + 64 + j];
#pragma unroll
    for (int o4 = 0; o4 < 4; ++o4) {
      float4 wv = *(const float4*)&sWt[c * 68 + q * 16 + o4 * 4];
      acc0[o4 * 4 + 0] = fmaf(x0, wv.x, acc0[o4 * 4 + 0]);
      acc0[o4 * 4 + 1] = fmaf(x0, wv.y, acc0[o4 * 4 + 1]);
      acc0[o4 * 4 + 2] = fmaf(x0, wv.z, acc0[o4 * 4 + 2]);
      acc0[o4 * 4 + 3] = fmaf(x0, wv.w, acc0[o4 * 4 + 3]);
      acc1[o4 * 4 + 0] = fmaf(x1, wv.x, acc1[o4 * 4 + 0]);
      acc1[o4 * 4 + 1] = fmaf(x1, wv.y, acc1[o4 * 4 + 1]);
      acc1[o4 * 4 + 2] = fmaf(x1, wv.z, acc1[o4 * 4 + 2]);
      acc1[o4 * 4 + 3] = fmaf(x1, wv.w, acc1[o4 * 4 + 3]);
    }
  }
  int n0 = base + j, n1 = base + 64 + j;
#pragma unroll
  for (int half = 0; half < 2; ++half) {
    int n = half ? n1 : n0;
    float* acc = half ? acc1 : acc0;
    if (n < NN) {
      if (doRelu) {
#pragma unroll
        for (int o = 0; o < 16; ++o) acc[o] = fmaxf(acc[o], 0.f);
      }
      if (doResid) {
#pragma unroll
        for (int o4 = 0; o4 < 4; ++o4) {
          float4 rv = *(const float4*)&resid[(size_t)n * 64 + q * 16 + o4 * 4];
          acc[o4 * 4 + 0] += rv.x; acc[o4 * 4 + 1] += rv.y;
          acc[o4 * 4 + 2] += rv.z; acc[o4 * 4 + 3] += rv.w;
        }
      }
#pragma unroll
      for (int o4 = 0; o4 < 4; ++o4) {
        float4 r;
        r.x = acc[o4 * 4 + 0]; r.y = acc[o4 * 4 + 1];
        r.z = acc[o4 * 4 + 2]; r.w = acc[o4 * 4 + 3];
        *(float4*)&out[(size_t)n * 64 + q * 16 + o4 * 4] = r;
      }
      if (outh) {
        uint4 u;
        u.x = f2h(acc[0], acc[1]);  u.y = f2h(acc[2], acc[3]);
        u.z = f2h(acc[4], acc[5]);  u.w = f2h(acc[6], acc[7]);
        outh[(size_t)n * 8 + q * 2] = u;
        u.x = f2h(acc[8], acc[9]);  u.y = f2h(acc[10], acc[11]);
        u.z = f2h(acc[12], acc[13]); u.w = f2h(acc[14], acc[15]);
        outh[(size_t)n * 8 + q * 2 + 1] = u;
      }
    }
  }
}

// ---------------- scoring / selection / output ----------------

__global__ __launch_bounds__(256) void score_k(const float* __restrict__ y,
                                               const float* __restrict__ wp,
                                               float* __restrict__ scores) {
  int tid = threadIdx.x;
  int lane = tid & 63, w = tid >> 6;
  int n = blockIdx.x * 4 + w;
  if (n >= NN) return;
  float wv = wp[lane];
  float s = wv * wv;
#pragma unroll
  for (int o = 32; o > 0; o >>= 1) s += __shfl_xor(s, o);
  float invn = 1.0f / sqrtf(s);
  float p = y[(size_t)n * 64 + lane] * wv;
#pragma unroll
  for (int o = 32; o > 0; o >>= 1) p += __shfl_xor(p, o);
  if (lane == 0) scores[n] = tanhf(p * invn);
}

__device__ __forceinline__ bool lexgt(float v1, int i1, float v2, int i2) {
  return (v1 > v2) || (v1 == v2 && i1 < i2);
}

// phase 1: 64 single-wave blocks, each emits its chunk's SORTED top-30.
// Chain depth P1D=13 (= max candidates one lane ingests) -> lossless, no spill.
__global__ __launch_bounds__(64, 1) void topk_p1(const float* __restrict__ score,
                                                 float* __restrict__ candv,
                                                 int* __restrict__ candi) {
  int lane = threadIdx.x;
  int base = blockIdx.x * P1CH;
  float lv[P1D]; int li[P1D];
#pragma unroll
  for (int k = 0; k < P1D; ++k) { lv[k] = -3.4e38f; li[k] = 0x7FFFFFFF; }
  for (int k = lane; k < P1CH; k += 64) {
    int idx = base + k;
    if (idx >= NN) break;
    float v = score[idx];
    if (lexgt(v, idx, lv[P1D - 1], li[P1D - 1])) {
      float cv = v; int ci = idx;
#pragma unroll
      for (int m = 0; m < P1D; ++m) {
        bool sw = lexgt(cv, ci, lv[m], li[m]);
        float tv = sw ? lv[m] : cv; int ti = sw ? li[m] : ci;
        lv[m] = sw ? cv : lv[m]; li[m] = sw ? ci : li[m];
        cv = tv; ci = ti;
      }
    }
  }
  for (int r = 0; r < TPK; ++r) {
    float bv = lv[0]; int bi = li[0];
#pragma unroll
    for (int o = 32; o > 0; o >>= 1) {
      float ov = __shfl_xor(bv, o); int oi = __shfl_xor(bi, o);
      if (lexgt(ov, oi, bv, bi)) { bv = ov; bi = oi; }
    }
    if (lane == 0) { candv[blockIdx.x * TPK + r] = bv; candi[blockIdx.x * TPK + r] = bi; }
    bool mine = (li[0] == bi);
#pragma unroll
    for (int m = 0; m < P1D - 1; ++m) {
      lv[m] = mine ? lv[m + 1] : lv[m];
      li[m] = mine ? li[m + 1] : li[m];
    }
    if (mine) { lv[P1D - 1] = -3.4e38f; li[P1D - 1] = 0x7FFFFFFF; }
  }
}

// phase 2 + final output: tournament merge of 64 sorted lists (lane b owns
// block b's pointer), then out[c] = max_r y[sel_r][c]*val_r. Candidates are
// staged in LDS once (coalesced) so each round is LDS + shfl only.
__global__ __launch_bounds__(64, 1) void topk_p2_final(const float* __restrict__ candv,
                                                       const int* __restrict__ candi,
                                                       const float* __restrict__ y,
                                                       float* __restrict__ out) {
  __shared__ float sv[P1B * TPK];
  __shared__ int si[P1B * TPK];
  __shared__ float sV[TPK];
  __shared__ int sI[TPK];
  int lane = threadIdx.x;  // 64
  for (int k = lane; k < P1B * TPK; k += 64) { sv[k] = candv[k]; si[k] = candi[k]; }
  __syncthreads();
  int myptr = 0;  // lane b's cursor into block b's sorted list
  for (int r = 0; r < TPK; ++r) {
    bool alive = (myptr < TPK);
    float hv = alive ? sv[lane * TPK + myptr] : -3.4e38f;
    int hi = alive ? si[lane * TPK + myptr] : 0x7FFFFFFF;
    float bv = hv; int bi = hi;
#pragma unroll
    for (int o = 32; o > 0; o >>= 1) {
      float ov = __shfl_xor(bv, o); int oi = __shfl_xor(bi, o);
      if (lexgt(ov, oi, bv, bi)) { bv = ov; bi = oi; }
    }
    if (alive && hi == bi) myptr++;  // node indices unique -> one winner
    if (lane == 0) { sV[r] = bv; sI[r] = bi; }
  }
  __syncthreads();
  float m = -3.4e38f;
  for (int r = 0; r < TPK; ++r)
    m = fmaxf(m, y[(size_t)sI[r] * 64 + lane] * sV[r]);
  out[lane] = m;
}

// ---------------- host orchestration ----------------

extern "C" void kernel_launch(void* const* d_in, const int* in_sizes, int n_in,
                              void* d_out, int out_size, void* d_ws, size_t ws_size,
                              hipStream_t stream) {
  const float* x = (const float*)d_in[0];
  const int* ei = (const int*)d_in[1];
  const float* Wl[5] = {(const float*)d_in[2], (const float*)d_in[4], (const float*)d_in[6],
                        (const float*)d_in[8], (const float*)d_in[10]};
  const float* bl[5] = {(const float*)d_in[3], (const float*)d_in[5], (const float*)d_in[7],
                        (const float*)d_in[9], (const float*)d_in[11]};
  const float* Wm = (const float*)d_in[12];
  const float* bm = (const float*)d_in[13];
  const float* wp = (const float*)d_in[14];
  float* out = (float*)d_out;

  uint8_t* base = (uint8_t*)d_ws;
  size_t off = 0;
  auto alloc = [&](size_t bytes) -> void* {
    void* p = base + off;
    off += (bytes + 255) & ~(size_t)255;
    return p;
  };
  int* deg = (int*)alloc(NN * 4);
  int* rowptr = (int*)alloc((NN + 1) * 4);
  int* cursor = (int*)alloc(NN * 4);
  float* dinv = (float*)alloc(NN * 4);
  int* bsum = (int*)alloc(SCNB * 4);
  int* boff = (int*)alloc(SCNB * 4);
  int2* meta = (int2*)alloc((size_t)NNZ * 8);
  float* x0 = (float*)alloc((size_t)NN * 4 * 4);
  float* t4a = (float*)alloc((size_t)NN * 4 * 4);
  float* t4b = (float*)alloc((size_t)NN * 4 * 4);
  float* xcur = (float*)alloc((size_t)NN * 64 * 4);
  float* tA = (float*)alloc((size_t)NN * 64 * 4);
  uint4* xh = (uint4*)alloc((size_t)NN * 64 * 2);   // fp16 x copy
  uint4* thA = (uint4*)alloc((size_t)NN * 64 * 2);  // fp16 state ping
  uint4* thB = (uint4*)alloc((size_t)NN * 64 * 2);  // fp16 state pong
  float* scores = (float*)alloc(NN * 4);
  float* candv = (float*)alloc((size_t)P1B * TPK * 4);
  int* candi = (int*)alloc((size_t)P1B * TPK * 4);

  const int* erow = ei;
  const int* ecol = ei + EE;

  init_deg<<<(NN + 255) / 256, 256, 0, stream>>>(deg);
  count_deg<<<(EE + 255) / 256, 256, 0, stream>>>(ecol, deg);
  scan_bsum<<<SCNB, 256, 0, stream>>>(deg, bsum);
  scan_boff<<<1, 256, 0, stream>>>(bsum, boff);
  scan_write<<<SCNB, 256, 0, stream>>>(deg, boff, rowptr, cursor, dinv);
  scatter_csr<<<(NNZ + 255) / 256, 256, 0, stream>>>(erow, ecol, dinv, cursor, meta);
  extract_x0<<<(NN + 255) / 256, 256, 0, stream>>>(x, (float4*)x0);

  const float AL[5] = {0.7f, 0.7f, 0.35f, 0.7f / 3.0f, 0.175f};

  // layer 0 (cin = 4, f32 — footprint is L2-resident)
  {
    float coef = (1.0f - AL[0]) / (float)KK;
    const float* tin = x0;
    float* tout = t4a;
    for (int k = 1; k <= KK; ++k) {
      float aacc = (k == KK) ? coef : 1.0f;
      float axc = (k == KK) ? AL[0] : 1.0f;
      sweep4<<<(NN + 63) / 64, 256, 0, stream>>>((const float4*)tin, (const float4*)x0,
                                                 (float4*)tout, rowptr, meta, aacc, axc);
      tin = tout;
      tout = (tout == t4a) ? t4b : t4a;
    }
    dense4<<<(NN + 3) / 4, 256, 0, stream>>>(tin, Wl[0], bl[0], xcur, (unsigned int*)xh);
  }
  // layers 1..4 (cin = 64, fp16 propagation state, 2 nodes/wave)
  for (int l = 1; l < 5; ++l) {
    float coef = (1.0f - AL[l]) / (float)KK;
    const uint4* tin = xh;
    uint4* tout = thA;
    for (int k = 1; k < KK; ++k) {
      sweep64h<<<(NN + 7) / 8, 256, 0, stream>>>(tin, xh, nullptr, tout, nullptr, rowptr, meta,
                                                 1.0f, 1.0f, 0);
      tin = tout;
      tout = (tout == thA) ? thB : thA;
    }
    // final sweep: gather fp16, combine with f32 x, write f32
    sweep64h<<<(NN + 7) / 8, 256, 0, stream>>>(tin, nullptr, (const float4*)xcur, nullptr,
                                               (float4*)tA, rowptr, meta, coef, AL[l], 1);
    dense64<<<(NN + DN - 1) / DN, 256, 0, stream>>>(tA, Wl[l], bl[l], xcur, xcur,
                                                    (l < 4) ? xh : nullptr, 1, (l >= 2) ? 1 : 0);
  }
  // final projection y = x @ Wm.T + bm  -> tA
  dense64<<<(NN + DN - 1) / DN, 256, 0, stream>>>(xcur, Wm, bm, nullptr, tA, nullptr, 0, 0);
  score_k<<<(NN + 3) / 4, 256, 0, stream>>>(tA, wp, scores);
  topk_p1<<<P1B, 64, 0, stream>>>(scores, candv, candi);
  topk_p2_final<<<1, 64, 0, stream>>>(candv, candi, tA, out);
}